// Round 2
// baseline (3830.330 us; speedup 1.0000x reference)
//
#include <hip/hip_runtime.h>
#include <math.h>

#define B_ 16
#define C_ 32
#define N_ 500
#define T_ 64
#define L_ 4
#define BSTR (C_*N_*T_)              // 1024000
#define CSTR (N_*T_)                 // 32000
#define TENS ((size_t)B_*C_*N_*T_)   // 16384000
#define CNT_ 512000.0
#define KB_ 20                       // k-block for diffusion (500 = 25*20 exact)

// ---------------------------------------------------------------------------
__global__ __launch_bounds__(256) void zero_kernel(double* __restrict__ p) {
  p[threadIdx.x] = 0.0;   // 256 doubles = L_*64 stats slots
}

// ---------------------------------------------------------------------------
// Per-channel sum / sum-of-squares for training-mode BatchNorm (fp64 exact).
// grid (C, B), 256 threads.
__global__ __launch_bounds__(256) void stats_kernel(const float* __restrict__ h,
                                                    double* __restrict__ st) {
  int c = blockIdx.x, b = blockIdx.y, tid = threadIdx.x;
  const float4* p = (const float4*)(h + (size_t)b*BSTR + (size_t)c*CSTR);
  double s = 0.0, s2 = 0.0;
  for (int i = tid; i < CSTR/4; i += 256) {
    float4 v = p[i];
    s  += (double)v.x + (double)v.y + (double)v.z + (double)v.w;
    s2 += (double)v.x*v.x + (double)v.y*v.y + (double)v.z*v.z + (double)v.w*v.w;
  }
  __shared__ double sd[256], sd2[256];
  sd[tid] = s; sd2[tid] = s2; __syncthreads();
  for (int off = 128; off > 0; off >>= 1) {
    if (tid < off) { sd[tid] += sd[tid+off]; sd2[tid] += sd2[tid+off]; }
    __syncthreads();
  }
  if (tid == 0) { atomicAdd(&st[2*c], sd[0]); atomicAdd(&st[2*c+1], sd2[0]); }
}

// ---------------------------------------------------------------------------
// Fused BN -> ReLU -> {res 1x1, causal convs K=3} -> tanh*sigmoid -> z (LDS)
// -> three 32x32 pointwise mixes: Y0 = ow0*z + gcb, Y1 = ow1*z, Y2 = ow2*z.
// One block per (b,n), 512 threads = (t:64) x (og:8), each thread 4 o's.
// Y0 may alias the input h (in-place safe: block reads only its own slice,
// fully staged to LDS, before writing the same slice).
__global__ __launch_bounds__(512) void fuse2_kernel(
    const float* __restrict__ h, const double* __restrict__ st,
    const float* __restrict__ gamma, const float* __restrict__ beta,
    const float* __restrict__ rw, const float* __restrict__ rb,
    const float* __restrict__ aw, const float* __restrict__ ab,
    const float* __restrict__ gw, const float* __restrict__ gb,
    const float* __restrict__ gcw, const float* __restrict__ gcb,
    float* __restrict__ Y0, float* __restrict__ Y1, float* __restrict__ Y2)
{
  __shared__ float sh_h[C_*T_];   // raw h [c][t]; reused later as z [o][t]
  __shared__ float sh_x[C_*68];   // relu(BN(h)) [c][4 pad + 64]
  __shared__ float ssc[C_], ssb[C_];

  int tid = threadIdx.x;
  int bx  = blockIdx.x;
  int b = bx / N_, n = bx - b*N_;
  size_t off = (size_t)b*BSTR + (size_t)n*T_;

  // stage h tile: 2048 floats, one float4 per thread
  int sc_ = tid >> 4, st4 = (tid & 15) << 2;
  float4 hv4 = *(const float4*)(h + off + (size_t)sc_*CSTR + st4);
  *(float4*)&sh_h[sc_*T_ + st4] = hv4;

  if (tid < C_) {
    double m = st[2*tid] * (1.0/CNT_);
    double v = st[2*tid+1] * (1.0/CNT_) - m*m;
    float sc = gamma[tid] * (float)(1.0 / sqrt(v + 1e-5));
    ssc[tid] = sc;
    ssb[tid] = beta[tid] - (float)m * sc;
  }
  if (tid < 128) { int c = tid >> 2; sh_x[c*68 + (tid & 3)] = 0.f; }
  __syncthreads();

  { // BN + ReLU from registers into padded sh_x
    float sc = ssc[sc_], sb = ssb[sc_];
    float4 r;
    r.x = fmaxf(fmaf(hv4.x, sc, sb), 0.f);
    r.y = fmaxf(fmaf(hv4.y, sc, sb), 0.f);
    r.z = fmaxf(fmaf(hv4.z, sc, sb), 0.f);
    r.w = fmaxf(fmaf(hv4.w, sc, sb), 0.f);
    *(float4*)&sh_x[sc_*68 + 4 + st4] = r;
  }
  __syncthreads();

  int t = tid & 63;
  int og = __builtin_amdgcn_readfirstlane(tid >> 6);  // wave-uniform 0..7
  float racc[4] = {0,0,0,0}, aacc[4] = {0,0,0,0}, gacc[4] = {0,0,0,0};
  for (int c = 0; c < C_; c++) {
    float hvv = sh_h[c*T_ + t];
    const float* xr = &sh_x[c*68 + 2 + t];
    float xm2 = xr[0], xm1 = xr[1], x0c = xr[2];
    #pragma unroll
    for (int jq = 0; jq < 4; jq++) {
      int oo = og*4 + jq;
      racc[jq] = fmaf(rw[oo*C_ + c], hvv, racc[jq]);
      const float* awp = aw + (oo*C_ + c)*3;
      const float* gwp = gw + (oo*C_ + c)*3;
      aacc[jq] = fmaf(awp[0], xm2, fmaf(awp[1], xm1, fmaf(awp[2], x0c, aacc[jq])));
      gacc[jq] = fmaf(gwp[0], xm2, fmaf(gwp[1], xm1, fmaf(gwp[2], x0c, gacc[jq])));
    }
  }
  float zv[4];
  #pragma unroll
  for (int jq = 0; jq < 4; jq++) {
    int oo = og*4 + jq;
    float a = aacc[jq] + racc[jq] + ab[oo] + rb[oo];
    float g = gacc[jq] + gb[oo];
    zv[jq] = tanhf(a) * (1.f/(1.f + expf(-g)));
  }
  __syncthreads();              // everyone done reading sh_h
  #pragma unroll
  for (int jq = 0; jq < 4; jq++) sh_h[(og*4 + jq)*T_ + t] = zv[jq];  // z[o][t]
  __syncthreads();

  // three 32->32 pointwise mixes
  float y0a[4] = {0,0,0,0}, y1a[4] = {0,0,0,0}, y2a[4] = {0,0,0,0};
  for (int c = 0; c < C_; c++) {
    float zc = sh_h[c*T_ + t];
    #pragma unroll
    for (int jq = 0; jq < 4; jq++) {
      const float* gr = gcw + (og*4 + jq)*96;
      y0a[jq] = fmaf(gr[c],      zc, y0a[jq]);
      y1a[jq] = fmaf(gr[32 + c], zc, y1a[jq]);
      y2a[jq] = fmaf(gr[64 + c], zc, y2a[jq]);
    }
  }
  #pragma unroll
  for (int jq = 0; jq < 4; jq++) {
    int oo = og*4 + jq;
    size_t p = off + (size_t)oo*CSTR + t;
    Y0[p] = y0a[jq] + gcb[oo];
    Y1[p] = y1a[jq];
    Y2[p] = y2a[jq];
  }
}

// ---------------------------------------------------------------------------
// Diffusion GEMM: out[b][o][w][t] = Y0 + sum_v A0[v][w]*Y1[o][v][t]
//                                       + sum_v A1[v][w]*Y2[o][v][t]
// (out aliases Y0 / bufA, accumulated in-place; tiles disjoint per block)
// grid ( (8 col-blocks x 8 t-blocks), B ). 256 thr = (i:64 row-grp, j:4 col-grp).
// Thread: rows = one o, 4 consecutive t; cols = 16 w. acc[4][16].
// A reads are wave-uniform -> scalar cache; Y via staged LDS tile.
__global__ __launch_bounds__(256, 2) void diff2_kernel(
    const float* __restrict__ Y1, const float* __restrict__ Y2,
    const float* __restrict__ A, float* __restrict__ out)
{
  __shared__ float Ys[2][KB_][256];   // [support][kk][row], 40 KB

  int tid = threadIdx.x;
  int i = tid & 63;
  int j = __builtin_amdgcn_readfirstlane(tid >> 6);   // 0..3, wave-uniform
  int bx = blockIdx.x;
  int cb = bx & 7, rb = bx >> 3;      // col fastest: L2 reuse of Y row-slice
  int b = blockIdx.y;

  int o  = i >> 1;
  int t0 = rb*8 + (i & 1)*4;          // 4 consecutive t
  int w0 = cb*64 + j*16;              // 16 cols

  const float* Y1b = Y1 + (size_t)b*BSTR;
  const float* Y2b = Y2 + (size_t)b*BSTR;

  float acc[4][16];
  #pragma unroll
  for (int r = 0; r < 4; r++)
    #pragma unroll
    for (int s = 0; s < 16; s++) acc[r][s] = 0.f;

  for (int v0 = 0; v0 < N_; v0 += KB_) {
    __syncthreads();
    // stage Y tiles: 2 * KB_ * 256 floats as float4 rows
    for (int idx = tid; idx < 2*KB_*64; idx += 256) {
      int s  = idx / (KB_*64);
      int rem = idx - s*(KB_*64);
      int kk = rem >> 6;
      int r4 = (rem & 63) << 2;                 // row base, multiple of 4
      int oo = r4 >> 3, tl = r4 & 7;            // 4 rows = same o, 4 consec t
      const float* src = (s ? Y2b : Y1b) +
          (size_t)oo*CSTR + (size_t)(v0 + kk)*T_ + rb*8 + tl;
      *(float4*)&Ys[s][kk][r4] = *(const float4*)src;
    }
    __syncthreads();
    for (int kk = 0; kk < KB_; kk++) {
      int v = v0 + kk;
      const float* a0p = A + (size_t)v*N_;
      const float* a1p = A + (size_t)N_*N_ + (size_t)v*N_;
      float a0[16], a1[16];
      #pragma unroll
      for (int q = 0; q < 4; q++) {
        int wb = w0 + q*4;
        int wc = (wb <= N_-4) ? wb : (N_-4);    // clamp: OOB lanes never store
        float4 u0 = *(const float4*)(a0p + wc);
        float4 u1 = *(const float4*)(a1p + wc);
        a0[q*4+0]=u0.x; a0[q*4+1]=u0.y; a0[q*4+2]=u0.z; a0[q*4+3]=u0.w;
        a1[q*4+0]=u1.x; a1[q*4+1]=u1.y; a1[q*4+2]=u1.z; a1[q*4+3]=u1.w;
      }
      float4 y1 = *(const float4*)&Ys[0][kk][4*i];
      float4 y2 = *(const float4*)&Ys[1][kk][4*i];
      #pragma unroll
      for (int s = 0; s < 16; s++) {
        float c0 = a0[s], c1 = a1[s];
        acc[0][s] = fmaf(c0, y1.x, acc[0][s]);
        acc[1][s] = fmaf(c0, y1.y, acc[1][s]);
        acc[2][s] = fmaf(c0, y1.z, acc[2][s]);
        acc[3][s] = fmaf(c0, y1.w, acc[3][s]);
        acc[0][s] = fmaf(c1, y2.x, acc[0][s]);
        acc[1][s] = fmaf(c1, y2.y, acc[1][s]);
        acc[2][s] = fmaf(c1, y2.z, acc[2][s]);
        acc[3][s] = fmaf(c1, y2.w, acc[3][s]);
      }
    }
  }

  float* ob = out + (size_t)b*BSTR + (size_t)o*CSTR + t0;
  #pragma unroll
  for (int s = 0; s < 16; s++) {
    int w = w0 + s;
    if (w < N_) {
      float* p = ob + (size_t)w*T_;
      float4 y0 = *(const float4*)p;
      y0.x += acc[0][s]; y0.y += acc[1][s];
      y0.z += acc[2][s]; y0.w += acc[3][s];
      *(float4*)p = y0;
    }
  }
}

// ---------------------------------------------------------------------------
// Online-softmax attention update for one stack slot.
// One block per (b,n), 256 thr = (t:64) x (g:4). MLP 32->64->64->1 per (t);
// then O += exp(e)*relu(h), s += exp(e). init=1 overwrites (slot 0 = x).
__global__ __launch_bounds__(256) void attn_kernel(
    const float* __restrict__ hsrc, float* __restrict__ O,
    float* __restrict__ sden,
    const float* __restrict__ W1, const float* __restrict__ b1,
    const float* __restrict__ W2, const float* __restrict__ b2,
    const float* __restrict__ w3, const float* __restrict__ b3,
    int init)
{
  __shared__ float xs[C_*T_];       // relu(h) [c][t]
  __shared__ float h1b[64*65];      // [o][t] padded
  __shared__ float part[4*T_];
  __shared__ float pw[T_];

  int tid = threadIdx.x;
  int t = tid & 63;
  int g = __builtin_amdgcn_readfirstlane(tid >> 6);  // 0..3
  int bx = blockIdx.x;
  int b = bx / N_, n = bx - b*N_;
  size_t off = (size_t)b*BSTR + (size_t)n*T_;

  for (int idx = tid; idx < 512; idx += 256) {
    int c = idx >> 4, q = (idx & 15) << 2;
    float4 v = *(const float4*)(hsrc + off + (size_t)c*CSTR + q);
    v.x = fmaxf(v.x, 0.f); v.y = fmaxf(v.y, 0.f);
    v.z = fmaxf(v.z, 0.f); v.w = fmaxf(v.w, 0.f);
    *(float4*)&xs[c*T_ + q] = v;
  }
  __syncthreads();

  { // phase A: h1[o0..o0+16) for this wave's g
    int o0 = g << 4;
    float h1r[16];
    #pragma unroll
    for (int k = 0; k < 16; k++) h1r[k] = b1[o0 + k];
    for (int c = 0; c < C_; c++) {
      float xv = xs[c*T_ + t];
      #pragma unroll
      for (int k = 0; k < 16; k++)
        h1r[k] = fmaf(W1[(o0 + k)*C_ + c], xv, h1r[k]);   // uniform -> s_load
    }
    #pragma unroll
    for (int k = 0; k < 16; k++) h1b[(o0 + k)*65 + t] = fmaxf(h1r[k], 0.f);
  }
  __syncthreads();
  { // phase B: 16 j-rows per wave, i inner with h1 from LDS (64 reads)
    int j0 = g << 4;
    float accj[16];
    #pragma unroll
    for (int jj = 0; jj < 16; jj++) accj[jj] = 0.f;
    for (int i = 0; i < 64; i++) {
      float hv = h1b[i*65 + t];
      #pragma unroll
      for (int jj = 0; jj < 16; jj++)
        accj[jj] = fmaf(W2[(j0 + jj)*64 + i], hv, accj[jj]);  // uniform
    }
    float ep = 0.f;
    #pragma unroll
    for (int jj = 0; jj < 16; jj++) {
      int jr = j0 + jj;
      ep = fmaf(w3[jr], fmaxf(b2[jr] + accj[jj], 0.f), ep);
    }
    part[g*T_ + t] = ep;
  }
  __syncthreads();
  if (tid < 64) {
    float e = b3[0] + part[t] + part[T_ + t] + part[2*T_ + t] + part[3*T_ + t];
    float p = expf(e);     // e is O(1): no max-subtraction needed
    pw[t] = p;
    size_t si = (size_t)b*CSTR + (size_t)n*T_ + t;
    float so = init ? 0.f : sden[si];
    sden[si] = so + p;
  }
  __syncthreads();
  for (int idx = tid; idx < 512; idx += 256) {
    int c = idx >> 4, q = (idx & 15) << 2;
    float4 xv = *(const float4*)&xs[c*T_ + q];
    float4 pv = *(const float4*)&pw[q];
    size_t p = off + (size_t)c*CSTR + q;
    float4 ov;
    if (init) ov = make_float4(0.f, 0.f, 0.f, 0.f);
    else      ov = *(const float4*)(O + p);
    ov.x = fmaf(pv.x, xv.x, ov.x);
    ov.y = fmaf(pv.y, xv.y, ov.y);
    ov.z = fmaf(pv.z, xv.z, ov.z);
    ov.w = fmaf(pv.w, xv.w, ov.w);
    *(float4*)(O + p) = ov;
  }
}

// ---------------------------------------------------------------------------
__global__ __launch_bounds__(256) void norm_kernel(float* __restrict__ O,
                                                   const float* __restrict__ sden) {
  unsigned idx = (blockIdx.x*256u + threadIdx.x) * 4u;   // < 16,384,000
  unsigned b = idx / BSTR;
  unsigned r = idx - b*BSTR;
  unsigned nt = r % CSTR;
  float4 o = *(float4*)(O + idx);
  const float* sp = sden + (size_t)b*CSTR + nt;
  o.x /= sp[0]; o.y /= sp[1]; o.z /= sp[2]; o.w /= sp[3];
  *(float4*)(O + idx) = o;
}

// ---------------------------------------------------------------------------
extern "C" void kernel_launch(void* const* d_in, const int* in_sizes, int n_in,
                              void* d_out, int out_size, void* d_ws, size_t ws_size,
                              hipStream_t stream)
{
  const float* x    = (const float*)d_in[0];
  const float* sup  = (const float*)d_in[1];
  const float* bng  = (const float*)d_in[2];
  const float* bnb  = (const float*)d_in[3];
  const float* rw   = (const float*)d_in[4];
  const float* rb   = (const float*)d_in[5];
  const float* aw   = (const float*)d_in[6];
  const float* ab   = (const float*)d_in[7];
  const float* gw   = (const float*)d_in[8];
  const float* gb   = (const float*)d_in[9];
  const float* gcw  = (const float*)d_in[10];
  const float* gcb  = (const float*)d_in[11];
  const float* w1   = (const float*)d_in[12];
  const float* ab1  = (const float*)d_in[13];
  const float* w2   = (const float*)d_in[14];
  const float* ab2  = (const float*)d_in[15];
  const float* w3   = (const float*)d_in[16];
  const float* ab3  = (const float*)d_in[17];
  float* out = (float*)d_out;

  // workspace: 3 tensors + sden + stats = 189.5 MiB
  float* ws   = (float*)d_ws;
  float* bufA = ws;                       // Y0 / layer output h
  float* bufB = ws + TENS;                // Y1
  float* bufC = ws + (size_t)2*TENS;      // Y2
  float* sden = ws + (size_t)3*TENS;      // [B,N,T] softmax denom
  double* st  = (double*)(ws + (size_t)3*TENS + (size_t)B_*N_*T_);

  zero_kernel<<<1, 256, 0, stream>>>(st);
  // slot 0 of the stack = x
  attn_kernel<<<B_*N_, 256, 0, stream>>>(x, out, sden, w1, ab1, w2, ab2, w3, ab3, 1);

  const float* hcur = x;
  for (int l = 0; l < L_; l++) {
    stats_kernel<<<dim3(C_, B_), 256, 0, stream>>>(hcur, st + l*64);
    fuse2_kernel<<<B_*N_, 512, 0, stream>>>(
        hcur, st + l*64, bng + l*C_, bnb + l*C_,
        rw + l*C_*C_, rb + l*C_,
        aw + l*C_*C_*3, ab + l*C_,
        gw + l*C_*C_*3, gb + l*C_,
        gcw + l*C_*96, gcb + l*C_,
        bufA, bufB, bufC);
    diff2_kernel<<<dim3(64, B_), 256, 0, stream>>>(bufB, bufC, sup, bufA);
    attn_kernel<<<B_*N_, 256, 0, stream>>>(bufA, out, sden, w1, ab1, w2, ab2, w3, ab3, 0);
    hcur = bufA;
  }
  norm_kernel<<<16000, 256, 0, stream>>>(out, sden);
}

// Round 3
// 2837.110 us; speedup vs baseline: 1.3501x; 1.3501x over previous
//
#include <hip/hip_runtime.h>
#include <hip/hip_bf16.h>
#include <math.h>

#define B_ 16
#define C_ 32
#define N_ 500
#define T_ 64
#define L_ 4
#define BSTR (C_*N_*T_)              // 1024000
#define CSTR (N_*T_)                 // 32000
#define TENS ((size_t)B_*C_*N_*T_)   // 16384000
#define CNT_ 512000.0

typedef short s8v __attribute__((ext_vector_type(8)));
typedef float f4v __attribute__((ext_vector_type(4)));

// ---------------------------------------------------------------------------
__global__ __launch_bounds__(256) void zero_kernel(double* __restrict__ p) {
  p[threadIdx.x] = 0.0;   // 256 doubles = L_*64 stats slots
}

// ---------------------------------------------------------------------------
// Per-channel sum / sum-of-squares for training-mode BatchNorm (fp64 exact).
__global__ __launch_bounds__(256) void stats_kernel(const float* __restrict__ h,
                                                    double* __restrict__ st) {
  int c = blockIdx.x, b = blockIdx.y, tid = threadIdx.x;
  const float4* p = (const float4*)(h + (size_t)b*BSTR + (size_t)c*CSTR);
  double s = 0.0, s2 = 0.0;
  for (int i = tid; i < CSTR/4; i += 256) {
    float4 v = p[i];
    s  += (double)v.x + (double)v.y + (double)v.z + (double)v.w;
    s2 += (double)v.x*v.x + (double)v.y*v.y + (double)v.z*v.z + (double)v.w*v.w;
  }
  __shared__ double sd[256], sd2[256];
  sd[tid] = s; sd2[tid] = s2; __syncthreads();
  for (int off = 128; off > 0; off >>= 1) {
    if (tid < off) { sd[tid] += sd[tid+off]; sd2[tid] += sd2[tid+off]; }
    __syncthreads();
  }
  if (tid == 0) { atomicAdd(&st[2*c], sd[0]); atomicAdd(&st[2*c+1], sd2[0]); }
}

// ---------------------------------------------------------------------------
// Build ATcat[w][k] bf16 hi/lo planes, w<512 (pad), k<1024 (two 512 supports).
// AT[w][k] = sup[s][v][w], s=k>>9, v=k&511; zero pads. One-time, ~1M elems.
__global__ __launch_bounds__(256) void aconv_kernel(const float* __restrict__ sup,
                                                    short* __restrict__ ATh,
                                                    short* __restrict__ ATl) {
  int idx = blockIdx.x*256 + threadIdx.x;   // 512*1024
  int k = idx & 1023, w = idx >> 10;
  int s = k >> 9, v = k & 511;
  float val = (v < N_ && w < N_) ? sup[((size_t)s*N_ + v)*N_ + w] : 0.f;
  __hip_bfloat16 bh = __float2bfloat16(val);
  float fh = __bfloat162float(bh);
  __hip_bfloat16 bl = __float2bfloat16(val - fh);
  ATh[idx] = *(short*)&bh;
  ATl[idx] = *(short*)&bl;
}

// ---------------------------------------------------------------------------
// Fused BN -> ReLU -> {res 1x1, causal convs K=3} -> tanh*sigmoid -> z (LDS)
// -> three 32x32 pointwise mixes: Y0 = ow0*z + gcb, Y1 = ow1*z, Y2 = ow2*z.
// One block per (b,n), 512 threads = (t:64) x (og:8). Y0 may alias input h.
__global__ __launch_bounds__(512) void fuse2_kernel(
    const float* __restrict__ h, const double* __restrict__ st,
    const float* __restrict__ gamma, const float* __restrict__ beta,
    const float* __restrict__ rw, const float* __restrict__ rb,
    const float* __restrict__ aw, const float* __restrict__ ab,
    const float* __restrict__ gw, const float* __restrict__ gb,
    const float* __restrict__ gcw, const float* __restrict__ gcb,
    float* __restrict__ Y0, float* __restrict__ Y1, float* __restrict__ Y2)
{
  __shared__ float sh_h[C_*T_];   // raw h [c][t]; reused later as z [o][t]
  __shared__ float sh_x[C_*68];   // relu(BN(h)) [c][4 pad + 64]
  __shared__ float ssc[C_], ssb[C_];

  int tid = threadIdx.x;
  int bx  = blockIdx.x;
  int b = bx / N_, n = bx - b*N_;
  size_t off = (size_t)b*BSTR + (size_t)n*T_;

  int sc_ = tid >> 4, st4 = (tid & 15) << 2;
  float4 hv4 = *(const float4*)(h + off + (size_t)sc_*CSTR + st4);
  *(float4*)&sh_h[sc_*T_ + st4] = hv4;

  if (tid < C_) {
    double m = st[2*tid] * (1.0/CNT_);
    double v = st[2*tid+1] * (1.0/CNT_) - m*m;
    float sc = gamma[tid] * (float)(1.0 / sqrt(v + 1e-5));
    ssc[tid] = sc;
    ssb[tid] = beta[tid] - (float)m * sc;
  }
  if (tid < 128) { int c = tid >> 2; sh_x[c*68 + (tid & 3)] = 0.f; }
  __syncthreads();

  {
    float sc = ssc[sc_], sb = ssb[sc_];
    float4 r;
    r.x = fmaxf(fmaf(hv4.x, sc, sb), 0.f);
    r.y = fmaxf(fmaf(hv4.y, sc, sb), 0.f);
    r.z = fmaxf(fmaf(hv4.z, sc, sb), 0.f);
    r.w = fmaxf(fmaf(hv4.w, sc, sb), 0.f);
    *(float4*)&sh_x[sc_*68 + 4 + st4] = r;
  }
  __syncthreads();

  int t = tid & 63;
  int og = __builtin_amdgcn_readfirstlane(tid >> 6);
  float racc[4] = {0,0,0,0}, aacc[4] = {0,0,0,0}, gacc[4] = {0,0,0,0};
  for (int c = 0; c < C_; c++) {
    float hvv = sh_h[c*T_ + t];
    const float* xr = &sh_x[c*68 + 2 + t];
    float xm2 = xr[0], xm1 = xr[1], x0c = xr[2];
    #pragma unroll
    for (int jq = 0; jq < 4; jq++) {
      int oo = og*4 + jq;
      racc[jq] = fmaf(rw[oo*C_ + c], hvv, racc[jq]);
      const float* awp = aw + (oo*C_ + c)*3;
      const float* gwp = gw + (oo*C_ + c)*3;
      aacc[jq] = fmaf(awp[0], xm2, fmaf(awp[1], xm1, fmaf(awp[2], x0c, aacc[jq])));
      gacc[jq] = fmaf(gwp[0], xm2, fmaf(gwp[1], xm1, fmaf(gwp[2], x0c, gacc[jq])));
    }
  }
  float zv[4];
  #pragma unroll
  for (int jq = 0; jq < 4; jq++) {
    int oo = og*4 + jq;
    float a = aacc[jq] + racc[jq] + ab[oo] + rb[oo];
    float g = gacc[jq] + gb[oo];
    zv[jq] = tanhf(a) * (1.f/(1.f + expf(-g)));
  }
  __syncthreads();
  #pragma unroll
  for (int jq = 0; jq < 4; jq++) sh_h[(og*4 + jq)*T_ + t] = zv[jq];
  __syncthreads();

  float y0a[4] = {0,0,0,0}, y1a[4] = {0,0,0,0}, y2a[4] = {0,0,0,0};
  for (int c = 0; c < C_; c++) {
    float zc = sh_h[c*T_ + t];
    #pragma unroll
    for (int jq = 0; jq < 4; jq++) {
      const float* gr = gcw + (og*4 + jq)*96;
      y0a[jq] = fmaf(gr[c],      zc, y0a[jq]);
      y1a[jq] = fmaf(gr[32 + c], zc, y1a[jq]);
      y2a[jq] = fmaf(gr[64 + c], zc, y2a[jq]);
    }
  }
  #pragma unroll
  for (int jq = 0; jq < 4; jq++) {
    int oo = og*4 + jq;
    size_t p = off + (size_t)oo*CSTR + t;
    Y0[p] = y0a[jq] + gcb[oo];
    Y1[p] = y1a[jq];
    Y2[p] = y2a[jq];
  }
}

// ---------------------------------------------------------------------------
// Diffusion via split-bf16 MFMA (fp32-equivalent: Yh*Ah + Yh*Al + Yl*Ah).
// Per b: out[m=(o,t), w] += sum_k Ycat[m,k] * ATcat[w,k], K=1024 (2x512 pad).
// Block tile 128(w) x 128(m); 4 waves, each 4x4 tiles of 16x16x32.
// out (bufA) holds Y0; epilogue does += (disjoint tiles).
// grid.x = mtile + 16*wtile: 4 w-tiles sharing a Y slice -> same XCD (L2).
__global__ __launch_bounds__(256) void diff3_kernel(
    const float* __restrict__ Y1, const float* __restrict__ Y2,
    const short* __restrict__ ATh, const short* __restrict__ ATl,
    float* __restrict__ out)
{
  __shared__ short Asd[2][128*40];   // AT tile [plane][w_local][k(32)+pad8]
  __shared__ short Bsd[2][128*40];   // Y  tile [plane][m_local][k(32)+pad8]

  int tid = threadIdx.x;
  int bx = blockIdx.x;
  int mtile = bx & 15, wtile = bx >> 4;
  int b = blockIdx.y;
  int w0 = wtile << 7;

  int lane = tid & 63;
  int wave = __builtin_amdgcn_readfirstlane(tid >> 6);
  int wi = wave & 1, wj = wave >> 1;
  int l15 = lane & 15, quad = lane >> 4;

  // fragment LDS offsets (element units), constant across K-steps
  int offA[4], offB[4];
  #pragma unroll
  for (int ti = 0; ti < 4; ti++) offA[ti] = (wi*64 + ti*16 + l15)*40 + quad*8;
  #pragma unroll
  for (int tj = 0; tj < 4; tj++) offB[tj] = (wj*64 + tj*16 + l15)*40 + quad*8;

  f4v acc[16];
  #pragma unroll
  for (int i = 0; i < 16; i++) acc[i] = (f4v){0.f, 0.f, 0.f, 0.f};

  int t_l = tid & 63;
  int g = tid >> 6;

  for (int k0 = 0; k0 < 1024; k0 += 32) {
    __syncthreads();
    // ---- stage A planes: 128 rows x 32 k x 2 planes = 1024 x 16B
    #pragma unroll
    for (int i = 0; i < 4; i++) {
      int idx = tid + i*256;
      int kq = idx & 3, wl = (idx >> 2) & 127, pl = idx >> 9;
      const short* sp = (pl ? ATl : ATh) + (size_t)(w0 + wl)*1024 + k0 + kq*8;
      int4 v = *(const int4*)sp;
      *(int4*)&Asd[pl][wl*40 + kq*8] = v;
    }
    // ---- stage B: Y fp32 -> split bf16, transposed (k contiguous per m)
    {
      int s  = k0 >> 9;
      int v0 = k0 & 511;
      const float* Ys = (s ? Y2 : Y1) + (size_t)b*BSTR;
      #pragma unroll
      for (int i = 0; i < 2; i++) {
        int sel = g*2 + i;           // 0..7 = (oo, k-quad)
        int oo = sel & 1, kq = sel >> 1;
        int o = mtile*2 + oo;
        int m = oo*64 + t_l;
        short hs[8], ls[8];
        #pragma unroll
        for (int j = 0; j < 8; j++) {
          int v = v0 + kq*8 + j;
          float val = (v < N_) ? Ys[((size_t)o*N_ + v)*T_ + t_l] : 0.f;
          __hip_bfloat16 bh = __float2bfloat16(val);
          float fh = __bfloat162float(bh);
          __hip_bfloat16 bl = __float2bfloat16(val - fh);
          hs[j] = *(short*)&bh;
          ls[j] = *(short*)&bl;
        }
        *(int4*)&Bsd[0][m*40 + kq*8] = *(const int4*)hs;
        *(int4*)&Bsd[1][m*40 + kq*8] = *(const int4*)ls;
      }
    }
    __syncthreads();
    // ---- fragments + MFMA (48 per wave per K-step)
    s8v ah[4], al[4], bh[4], bl[4];
    #pragma unroll
    for (int ti = 0; ti < 4; ti++) {
      ah[ti] = *(const s8v*)&Asd[0][offA[ti]];
      al[ti] = *(const s8v*)&Asd[1][offA[ti]];
    }
    #pragma unroll
    for (int tj = 0; tj < 4; tj++) {
      bh[tj] = *(const s8v*)&Bsd[0][offB[tj]];
      bl[tj] = *(const s8v*)&Bsd[1][offB[tj]];
    }
    #pragma unroll
    for (int ti = 0; ti < 4; ti++)
      #pragma unroll
      for (int tj = 0; tj < 4; tj++) {
        f4v d = acc[ti*4+tj];
        d = __builtin_amdgcn_mfma_f32_16x16x32_bf16(ah[ti], bh[tj], d, 0, 0, 0);
        d = __builtin_amdgcn_mfma_f32_16x16x32_bf16(ah[ti], bl[tj], d, 0, 0, 0);
        d = __builtin_amdgcn_mfma_f32_16x16x32_bf16(al[ti], bh[tj], d, 0, 0, 0);
        acc[ti*4+tj] = d;
      }
  }

  // ---- epilogue: out[b][o][w][t] += acc  (C/D: col=lane&15, row=quad*4+reg)
  #pragma unroll
  for (int tj = 0; tj < 4; tj++) {
    int o = mtile*2 + wj;            // m = mtile*128 + wj*64 + tj*16 + l15
    int t = tj*16 + l15;
    float* obase = out + (((size_t)b*C_ + o)*N_)*T_ + t;
    #pragma unroll
    for (int ti = 0; ti < 4; ti++) {
      int wbase = w0 + wi*64 + ti*16 + quad*4;
      #pragma unroll
      for (int r = 0; r < 4; r++) {
        int w = wbase + r;
        if (w < N_) {
          float* p = obase + (size_t)w*T_;
          *p += acc[ti*4+tj][r];
        }
      }
    }
  }
}

// ---------------------------------------------------------------------------
// Online-softmax attention update for one stack slot.
__global__ __launch_bounds__(256) void attn_kernel(
    const float* __restrict__ hsrc, float* __restrict__ O,
    float* __restrict__ sden,
    const float* __restrict__ W1, const float* __restrict__ b1,
    const float* __restrict__ W2, const float* __restrict__ b2,
    const float* __restrict__ w3, const float* __restrict__ b3,
    int init)
{
  __shared__ float xs[C_*T_];
  __shared__ float h1b[64*65];
  __shared__ float part[4*T_];
  __shared__ float pw[T_];

  int tid = threadIdx.x;
  int t = tid & 63;
  int g = __builtin_amdgcn_readfirstlane(tid >> 6);
  int bx = blockIdx.x;
  int b = bx / N_, n = bx - b*N_;
  size_t off = (size_t)b*BSTR + (size_t)n*T_;

  for (int idx = tid; idx < 512; idx += 256) {
    int c = idx >> 4, q = (idx & 15) << 2;
    float4 v = *(const float4*)(hsrc + off + (size_t)c*CSTR + q);
    v.x = fmaxf(v.x, 0.f); v.y = fmaxf(v.y, 0.f);
    v.z = fmaxf(v.z, 0.f); v.w = fmaxf(v.w, 0.f);
    *(float4*)&xs[c*T_ + q] = v;
  }
  __syncthreads();

  {
    int o0 = g << 4;
    float h1r[16];
    #pragma unroll
    for (int k = 0; k < 16; k++) h1r[k] = b1[o0 + k];
    for (int c = 0; c < C_; c++) {
      float xv = xs[c*T_ + t];
      #pragma unroll
      for (int k = 0; k < 16; k++)
        h1r[k] = fmaf(W1[(o0 + k)*C_ + c], xv, h1r[k]);
    }
    #pragma unroll
    for (int k = 0; k < 16; k++) h1b[(o0 + k)*65 + t] = fmaxf(h1r[k], 0.f);
  }
  __syncthreads();
  {
    int j0 = g << 4;
    float accj[16];
    #pragma unroll
    for (int jj = 0; jj < 16; jj++) accj[jj] = 0.f;
    for (int i = 0; i < 64; i++) {
      float hv = h1b[i*65 + t];
      #pragma unroll
      for (int jj = 0; jj < 16; jj++)
        accj[jj] = fmaf(W2[(j0 + jj)*64 + i], hv, accj[jj]);
    }
    float ep = 0.f;
    #pragma unroll
    for (int jj = 0; jj < 16; jj++) {
      int jr = j0 + jj;
      ep = fmaf(w3[jr], fmaxf(b2[jr] + accj[jj], 0.f), ep);
    }
    part[g*T_ + t] = ep;
  }
  __syncthreads();
  if (tid < 64) {
    float e = b3[0] + part[t] + part[T_ + t] + part[2*T_ + t] + part[3*T_ + t];
    float p = expf(e);
    pw[t] = p;
    size_t si = (size_t)b*CSTR + (size_t)n*T_ + t;
    float so = init ? 0.f : sden[si];
    sden[si] = so + p;
  }
  __syncthreads();
  for (int idx = tid; idx < 512; idx += 256) {
    int c = idx >> 4, q = (idx & 15) << 2;
    float4 xv = *(const float4*)&xs[c*T_ + q];
    float4 pv = *(const float4*)&pw[q];
    size_t p = off + (size_t)c*CSTR + q;
    float4 ov;
    if (init) ov = make_float4(0.f, 0.f, 0.f, 0.f);
    else      ov = *(const float4*)(O + p);
    ov.x = fmaf(pv.x, xv.x, ov.x);
    ov.y = fmaf(pv.y, xv.y, ov.y);
    ov.z = fmaf(pv.z, xv.z, ov.z);
    ov.w = fmaf(pv.w, xv.w, ov.w);
    *(float4*)(O + p) = ov;
  }
}

// ---------------------------------------------------------------------------
__global__ __launch_bounds__(256) void norm_kernel(float* __restrict__ O,
                                                   const float* __restrict__ sden) {
  unsigned idx = (blockIdx.x*256u + threadIdx.x) * 4u;
  unsigned b = idx / BSTR;
  unsigned r = idx - b*BSTR;
  unsigned nt = r % CSTR;
  float4 o = *(float4*)(O + idx);
  const float* sp = sden + (size_t)b*CSTR + nt;
  o.x /= sp[0]; o.y /= sp[1]; o.z /= sp[2]; o.w /= sp[3];
  *(float4*)(O + idx) = o;
}

// ---------------------------------------------------------------------------
extern "C" void kernel_launch(void* const* d_in, const int* in_sizes, int n_in,
                              void* d_out, int out_size, void* d_ws, size_t ws_size,
                              hipStream_t stream)
{
  const float* x    = (const float*)d_in[0];
  const float* sup  = (const float*)d_in[1];
  const float* bng  = (const float*)d_in[2];
  const float* bnb  = (const float*)d_in[3];
  const float* rw   = (const float*)d_in[4];
  const float* rb   = (const float*)d_in[5];
  const float* aw   = (const float*)d_in[6];
  const float* ab   = (const float*)d_in[7];
  const float* gw   = (const float*)d_in[8];
  const float* gb   = (const float*)d_in[9];
  const float* gcw  = (const float*)d_in[10];
  const float* gcb  = (const float*)d_in[11];
  const float* w1   = (const float*)d_in[12];
  const float* ab1  = (const float*)d_in[13];
  const float* w2   = (const float*)d_in[14];
  const float* ab2  = (const float*)d_in[15];
  const float* w3   = (const float*)d_in[16];
  const float* ab3  = (const float*)d_in[17];
  float* out = (float*)d_out;

  // workspace: 3 tensors + sden + stats + AT planes  (~194 MiB)
  float* ws   = (float*)d_ws;
  float* bufA = ws;                       // Y0 / layer output h
  float* bufB = ws + TENS;                // Y1
  float* bufC = ws + (size_t)2*TENS;      // Y2
  float* sden = ws + (size_t)3*TENS;      // [B,N,T] softmax denom
  double* st  = (double*)(ws + (size_t)3*TENS + (size_t)B_*N_*T_);
  short* ATh  = (short*)(ws + (size_t)3*TENS + (size_t)B_*N_*T_ + 512);
  short* ATl  = ATh + (size_t)512*1024;

  zero_kernel<<<1, 256, 0, stream>>>(st);
  aconv_kernel<<<2048, 256, 0, stream>>>(sup, ATh, ATl);
  // slot 0 of the stack = x
  attn_kernel<<<B_*N_, 256, 0, stream>>>(x, out, sden, w1, ab1, w2, ab2, w3, ab3, 1);

  const float* hcur = x;
  for (int l = 0; l < L_; l++) {
    stats_kernel<<<dim3(C_, B_), 256, 0, stream>>>(hcur, st + l*64);
    fuse2_kernel<<<B_*N_, 512, 0, stream>>>(
        hcur, st + l*64, bng + l*C_, bnb + l*C_,
        rw + l*C_*C_, rb + l*C_,
        aw + l*C_*C_*3, ab + l*C_,
        gw + l*C_*C_*3, gb + l*C_,
        gcw + l*C_*96, gcb + l*C_,
        bufA, bufB, bufC);
    diff3_kernel<<<dim3(64, B_), 256, 0, stream>>>(bufB, bufC, ATh, ATl, bufA);
    attn_kernel<<<B_*N_, 256, 0, stream>>>(bufA, out, sden, w1, ab1, w2, ab2, w3, ab3, 0);
    hcur = bufA;
  }
  norm_kernel<<<16000, 256, 0, stream>>>(out, sden);
}

// Round 4
// 2194.409 us; speedup vs baseline: 1.7455x; 1.2929x over previous
//
#include <hip/hip_runtime.h>
#include <hip/hip_bf16.h>
#include <math.h>

#define B_ 16
#define C_ 32
#define N_ 500
#define T_ 64
#define L_ 4
#define BSTR (C_*N_*T_)              // 1024000
#define CSTR (N_*T_)                 // 32000
#define TENS ((size_t)B_*C_*N_*T_)   // 16384000
#define CNT_ 512000.0

typedef short s8v __attribute__((ext_vector_type(8)));
typedef float f4v __attribute__((ext_vector_type(4)));

// ---------------------------------------------------------------------------
__global__ __launch_bounds__(256) void zero_kernel(double* __restrict__ p) {
  p[threadIdx.x] = 0.0;   // 256 doubles = L_*64 stats slots
}

// ---------------------------------------------------------------------------
// Per-channel sum/sum-sq for BN, layer 0 only (reads x). fp64 exact.
__global__ __launch_bounds__(256) void stats_kernel(const float* __restrict__ h,
                                                    double* __restrict__ st) {
  int c = blockIdx.x, b = blockIdx.y, tid = threadIdx.x;
  const float4* p = (const float4*)(h + (size_t)b*BSTR + (size_t)c*CSTR);
  double s = 0.0, s2 = 0.0;
  for (int i = tid; i < CSTR/4; i += 256) {
    float4 v = p[i];
    s  += (double)v.x + (double)v.y + (double)v.z + (double)v.w;
    s2 += (double)v.x*v.x + (double)v.y*v.y + (double)v.z*v.z + (double)v.w*v.w;
  }
  __shared__ double sd[256], sd2[256];
  sd[tid] = s; sd2[tid] = s2; __syncthreads();
  for (int off = 128; off > 0; off >>= 1) {
    if (tid < off) { sd[tid] += sd[tid+off]; sd2[tid] += sd2[tid+off]; }
    __syncthreads();
  }
  if (tid == 0) { atomicAdd(&st[2*c], sd[0]); atomicAdd(&st[2*c+1], sd2[0]); }
}

// ---------------------------------------------------------------------------
// Build ATcat[w][k] bf16 hi/lo planes, w<512 (pad), k<1024 (two 512 supports).
__global__ __launch_bounds__(256) void aconv_kernel(const float* __restrict__ sup,
                                                    short* __restrict__ ATh,
                                                    short* __restrict__ ATl) {
  int idx = blockIdx.x*256 + threadIdx.x;   // 512*1024
  int k = idx & 1023, w = idx >> 10;
  int s = k >> 9, v = k & 511;
  float val = (v < N_ && w < N_) ? sup[((size_t)s*N_ + v)*N_ + w] : 0.f;
  __hip_bfloat16 bh = __float2bfloat16(val);
  float fh = __bfloat162float(bh);
  __hip_bfloat16 bl = __float2bfloat16(val - fh);
  ATh[idx] = *(short*)&bh;
  ATl[idx] = *(short*)&bl;
}

// ---------------------------------------------------------------------------
// One-time W1 transpose: W1T[c][k] = W1[k][c], 2048 elems.
__global__ __launch_bounds__(256) void w1t_kernel(const float* __restrict__ W1,
                                                  float* __restrict__ W1T) {
  int idx = blockIdx.x*256 + threadIdx.x;   // 2048
  int c = idx >> 6, k = idx & 63;
  W1T[c*64 + k] = W1[k*32 + c];
}

// ---------------------------------------------------------------------------
// Fused BN -> ReLU -> {res 1x1, causal convs K=3} -> tanh*sigmoid -> z (LDS)
// -> three 32x32 pointwise mixes. TWO nodes per block (doubles FMA per
// wave-uniform weight s_load — scalar pipe was the round-3 limiter).
// 512 threads = (t:64) x (og:8). Y0 may alias input h (reads fully staged).
__global__ __launch_bounds__(512) void fuse3_kernel(
    const float* __restrict__ h, const double* __restrict__ st,
    const float* __restrict__ gamma, const float* __restrict__ beta,
    const float* __restrict__ rw, const float* __restrict__ rb,
    const float* __restrict__ aw, const float* __restrict__ ab,
    const float* __restrict__ gw, const float* __restrict__ gb,
    const float* __restrict__ gcw, const float* __restrict__ gcb,
    float* __restrict__ Y0, float* __restrict__ Y1, float* __restrict__ Y2)
{
  __shared__ float sh_h[2][C_*T_];   // raw h [nn][c][t]; later z [nn][o][t]
  __shared__ float sh_x[2][C_*68];   // relu(BN(h)) [nn][c][4 pad + 64]
  __shared__ float ssc[C_], ssb[C_];

  int tid = threadIdx.x;
  int bx  = blockIdx.x;
  int b = bx / 250, np = bx - b*250;
  size_t off0 = (size_t)b*BSTR + (size_t)(np*2)*T_;

  #pragma unroll
  for (int i = 0; i < 2; i++) {      // stage 2 nodes: 1024 float4
    int idx = tid + i*512;
    int nn = idx >> 9, r = idx & 511;
    int c = r >> 4, t4 = (r & 15) << 2;
    float4 v = *(const float4*)(h + off0 + (size_t)nn*T_ + (size_t)c*CSTR + t4);
    *(float4*)&sh_h[nn][c*T_ + t4] = v;
  }
  if (tid < C_) {
    double m = st[2*tid] * (1.0/CNT_);
    double v = st[2*tid+1] * (1.0/CNT_) - m*m;
    float sc = gamma[tid] * (float)(1.0 / sqrt(v + 1e-5));
    ssc[tid] = sc;
    ssb[tid] = beta[tid] - (float)m * sc;
  }
  if (tid < 256) { int nn = tid >> 7, c = (tid >> 2) & 31; sh_x[nn][c*68 + (tid & 3)] = 0.f; }
  __syncthreads();

  #pragma unroll
  for (int i = 0; i < 2; i++) {      // BN + ReLU into padded sh_x
    int idx = tid + i*512;
    int nn = idx >> 9, r = idx & 511;
    int c = r >> 4, t4 = (r & 15) << 2;
    float sc = ssc[c], sb = ssb[c];
    float4 v = *(const float4*)&sh_h[nn][c*T_ + t4];
    float4 rr;
    rr.x = fmaxf(fmaf(v.x, sc, sb), 0.f);
    rr.y = fmaxf(fmaf(v.y, sc, sb), 0.f);
    rr.z = fmaxf(fmaf(v.z, sc, sb), 0.f);
    rr.w = fmaxf(fmaf(v.w, sc, sb), 0.f);
    *(float4*)&sh_x[nn][c*68 + 4 + t4] = rr;
  }
  __syncthreads();

  int t = tid & 63;
  int og = __builtin_amdgcn_readfirstlane(tid >> 6);   // 0..7
  float racc[2][4] = {}, aacc[2][4] = {}, gacc[2][4] = {};
  for (int c = 0; c < C_; c++) {
    float wR[4], wA[4][3], wG[4][3];   // wave-uniform -> SGPRs
    #pragma unroll
    for (int jq = 0; jq < 4; jq++) {
      int oo = og*4 + jq;
      wR[jq] = rw[oo*C_ + c];
      const float* ap = aw + (oo*C_ + c)*3;
      const float* gp = gw + (oo*C_ + c)*3;
      wA[jq][0] = ap[0]; wA[jq][1] = ap[1]; wA[jq][2] = ap[2];
      wG[jq][0] = gp[0]; wG[jq][1] = gp[1]; wG[jq][2] = gp[2];
    }
    #pragma unroll
    for (int nn = 0; nn < 2; nn++) {
      float hvv = sh_h[nn][c*T_ + t];
      const float* xr = &sh_x[nn][c*68 + 2 + t];
      float xm2 = xr[0], xm1 = xr[1], x0c = xr[2];
      #pragma unroll
      for (int jq = 0; jq < 4; jq++) {
        racc[nn][jq] = fmaf(wR[jq], hvv, racc[nn][jq]);
        aacc[nn][jq] = fmaf(wA[jq][0], xm2, fmaf(wA[jq][1], xm1, fmaf(wA[jq][2], x0c, aacc[nn][jq])));
        gacc[nn][jq] = fmaf(wG[jq][0], xm2, fmaf(wG[jq][1], xm1, fmaf(wG[jq][2], x0c, gacc[nn][jq])));
      }
    }
  }
  float zv[2][4];
  #pragma unroll
  for (int nn = 0; nn < 2; nn++)
    #pragma unroll
    for (int jq = 0; jq < 4; jq++) {
      int oo = og*4 + jq;
      float a = aacc[nn][jq] + racc[nn][jq] + ab[oo] + rb[oo];
      float gg = gacc[nn][jq] + gb[oo];
      zv[nn][jq] = tanhf(a) * (1.f/(1.f + expf(-gg)));
    }
  __syncthreads();
  #pragma unroll
  for (int nn = 0; nn < 2; nn++)
    #pragma unroll
    for (int jq = 0; jq < 4; jq++) sh_h[nn][(og*4 + jq)*T_ + t] = zv[nn][jq];
  __syncthreads();

  float y0a[2][4] = {}, y1a[2][4] = {}, y2a[2][4] = {};
  for (int c = 0; c < C_; c++) {
    float g0[4], g1[4], g2[4];
    #pragma unroll
    for (int jq = 0; jq < 4; jq++) {
      const float* gr = gcw + (og*4 + jq)*96;
      g0[jq] = gr[c]; g1[jq] = gr[32 + c]; g2[jq] = gr[64 + c];
    }
    #pragma unroll
    for (int nn = 0; nn < 2; nn++) {
      float zc = sh_h[nn][c*T_ + t];
      #pragma unroll
      for (int jq = 0; jq < 4; jq++) {
        y0a[nn][jq] = fmaf(g0[jq], zc, y0a[nn][jq]);
        y1a[nn][jq] = fmaf(g1[jq], zc, y1a[nn][jq]);
        y2a[nn][jq] = fmaf(g2[jq], zc, y2a[nn][jq]);
      }
    }
  }
  #pragma unroll
  for (int nn = 0; nn < 2; nn++)
    #pragma unroll
    for (int jq = 0; jq < 4; jq++) {
      int oo = og*4 + jq;
      size_t pp = off0 + (size_t)nn*T_ + (size_t)oo*CSTR + t;
      Y0[pp] = y0a[nn][jq] + gcb[oo];
      Y1[pp] = y1a[nn][jq];
      Y2[pp] = y2a[nn][jq];
    }
}

// ---------------------------------------------------------------------------
// Diffusion via split-bf16 MFMA + fused next-layer BN stats in the epilogue.
__global__ __launch_bounds__(256) void diff3_kernel(
    const float* __restrict__ Y1, const float* __restrict__ Y2,
    const short* __restrict__ ATh, const short* __restrict__ ATl,
    float* __restrict__ out, double* __restrict__ stp)
{
  __shared__ short Asd[2][128*40];   // AT tile [plane][w_local][k(32)+pad8]
  __shared__ short Bsd[2][128*40];   // Y  tile [plane][m_local][k(32)+pad8]

  int tid = threadIdx.x;
  int bx = blockIdx.x;
  int mtile = bx & 15, wtile = bx >> 4;
  int b = blockIdx.y;
  int w0 = wtile << 7;

  int lane = tid & 63;
  int wave = __builtin_amdgcn_readfirstlane(tid >> 6);
  int wi = wave & 1, wj = wave >> 1;
  int l15 = lane & 15, quad = lane >> 4;

  int offA[4], offB[4];
  #pragma unroll
  for (int ti = 0; ti < 4; ti++) offA[ti] = (wi*64 + ti*16 + l15)*40 + quad*8;
  #pragma unroll
  for (int tj = 0; tj < 4; tj++) offB[tj] = (wj*64 + tj*16 + l15)*40 + quad*8;

  f4v acc[16];
  #pragma unroll
  for (int i = 0; i < 16; i++) acc[i] = (f4v){0.f, 0.f, 0.f, 0.f};

  int t_l = tid & 63;
  int g = tid >> 6;

  for (int k0 = 0; k0 < 1024; k0 += 32) {
    __syncthreads();
    #pragma unroll
    for (int i = 0; i < 4; i++) {
      int idx = tid + i*256;
      int kq = idx & 3, wl = (idx >> 2) & 127, pl = idx >> 9;
      const short* sp = (pl ? ATl : ATh) + (size_t)(w0 + wl)*1024 + k0 + kq*8;
      int4 v = *(const int4*)sp;
      *(int4*)&Asd[pl][wl*40 + kq*8] = v;
    }
    {
      int s  = k0 >> 9;
      int v0 = k0 & 511;
      const float* Ys = (s ? Y2 : Y1) + (size_t)b*BSTR;
      #pragma unroll
      for (int i = 0; i < 2; i++) {
        int sel = g*2 + i;
        int oo = sel & 1, kq = sel >> 1;
        int o = mtile*2 + oo;
        int m = oo*64 + t_l;
        short hs[8], ls[8];
        #pragma unroll
        for (int j = 0; j < 8; j++) {
          int v = v0 + kq*8 + j;
          float val = (v < N_) ? Ys[((size_t)o*N_ + v)*T_ + t_l] : 0.f;
          __hip_bfloat16 bh = __float2bfloat16(val);
          float fh = __bfloat162float(bh);
          __hip_bfloat16 bl = __float2bfloat16(val - fh);
          hs[j] = *(short*)&bh;
          ls[j] = *(short*)&bl;
        }
        *(int4*)&Bsd[0][m*40 + kq*8] = *(const int4*)hs;
        *(int4*)&Bsd[1][m*40 + kq*8] = *(const int4*)ls;
      }
    }
    __syncthreads();
    s8v ah[4], al[4], bh[4], bl[4];
    #pragma unroll
    for (int ti = 0; ti < 4; ti++) {
      ah[ti] = *(const s8v*)&Asd[0][offA[ti]];
      al[ti] = *(const s8v*)&Asd[1][offA[ti]];
    }
    #pragma unroll
    for (int tj = 0; tj < 4; tj++) {
      bh[tj] = *(const s8v*)&Bsd[0][offB[tj]];
      bl[tj] = *(const s8v*)&Bsd[1][offB[tj]];
    }
    #pragma unroll
    for (int ti = 0; ti < 4; ti++)
      #pragma unroll
      for (int tj = 0; tj < 4; tj++) {
        f4v d = acc[ti*4+tj];
        d = __builtin_amdgcn_mfma_f32_16x16x32_bf16(ah[ti], bh[tj], d, 0, 0, 0);
        d = __builtin_amdgcn_mfma_f32_16x16x32_bf16(ah[ti], bl[tj], d, 0, 0, 0);
        d = __builtin_amdgcn_mfma_f32_16x16x32_bf16(al[ti], bh[tj], d, 0, 0, 0);
        acc[ti*4+tj] = d;
      }
  }

  // epilogue: out += acc; capture final values for next layer's BN stats.
  // All of a thread's tiles belong to one o (o = mtile*2 + wj).
  int o = mtile*2 + wj;
  float s = 0.f, s2 = 0.f;
  #pragma unroll
  for (int tj = 0; tj < 4; tj++) {
    int t = tj*16 + l15;
    float* obase = out + (((size_t)b*C_ + o)*N_)*T_ + t;
    #pragma unroll
    for (int ti = 0; ti < 4; ti++) {
      int wbase = w0 + wi*64 + ti*16 + quad*4;
      #pragma unroll
      for (int r = 0; r < 4; r++) {
        int w = wbase + r;
        if (w < N_) {
          float* p = obase + (size_t)w*T_;
          float val = *p + acc[ti*4+tj][r];
          *p = val;
          s += val;
          s2 = fmaf(val, val, s2);
        }
      }
    }
  }
  if (stp) {
    #pragma unroll
    for (int d = 32; d > 0; d >>= 1) {
      s  += __shfl_down(s,  d, 64);
      s2 += __shfl_down(s2, d, 64);
    }
    if (lane == 0) {
      atomicAdd(&stp[2*o],     (double)s);
      atomicAdd(&stp[2*o + 1], (double)s2);
    }
  }
}

// ---------------------------------------------------------------------------
// Online-softmax attention, one node per wave, MLP fully in registers.
// Weight streams are contiguous s_load_dwordx16 batches; no LDS.
__global__ __launch_bounds__(256) void attn3_kernel(
    const float* __restrict__ hsrc, float* __restrict__ O,
    float* __restrict__ sden,
    const float* __restrict__ W1T, const float* __restrict__ b1,
    const float* __restrict__ W2, const float* __restrict__ b2,
    const float* __restrict__ w3, const float* __restrict__ b3,
    int init)
{
  int tid = threadIdx.x;
  int t = tid & 63;
  int g = __builtin_amdgcn_readfirstlane(tid >> 6);
  int bx = blockIdx.x;
  int b = bx / 125;
  int n = (bx - b*125)*4 + g;
  size_t off = (size_t)b*BSTR + (size_t)n*T_;

  float h1r[64];
  #pragma unroll
  for (int k = 0; k < 64; k++) h1r[k] = b1[k];
  for (int c = 0; c < C_; c++) {
    float xv = fmaxf(hsrc[off + (size_t)c*CSTR + t], 0.f);
    const float* wr = W1T + c*64;
    #pragma unroll
    for (int k = 0; k < 64; k++) h1r[k] = fmaf(wr[k], xv, h1r[k]);
  }
  #pragma unroll
  for (int k = 0; k < 64; k++) h1r[k] = fmaxf(h1r[k], 0.f);

  float e = b3[0];
  for (int j = 0; j < 64; j++) {
    const float* w2r = W2 + j*64;
    float a0 = 0.f, a1 = 0.f, a2 = 0.f, a3 = 0.f;
    #pragma unroll
    for (int i = 0; i < 64; i += 4) {
      a0 = fmaf(w2r[i+0], h1r[i+0], a0);
      a1 = fmaf(w2r[i+1], h1r[i+1], a1);
      a2 = fmaf(w2r[i+2], h1r[i+2], a2);
      a3 = fmaf(w2r[i+3], h1r[i+3], a3);
    }
    float a = b2[j] + ((a0+a1)+(a2+a3));
    e = fmaf(w3[j], fmaxf(a, 0.f), e);
  }
  float p = expf(e);      // e is O(1): no max-subtraction needed

  size_t si = (size_t)b*CSTR + (size_t)n*T_ + t;
  float so = init ? 0.f : sden[si];
  sden[si] = so + p;

  for (int c = 0; c < C_; c++) {
    size_t pi = off + (size_t)c*CSTR + t;
    float xv = fmaxf(hsrc[pi], 0.f);      // L1-hit re-read
    float ov = init ? 0.f : O[pi];
    O[pi] = fmaf(p, xv, ov);
  }
}

// ---------------------------------------------------------------------------
__global__ __launch_bounds__(256) void norm_kernel(float* __restrict__ O,
                                                   const float* __restrict__ sden) {
  unsigned idx = (blockIdx.x*256u + threadIdx.x) * 4u;
  unsigned b = idx / BSTR;
  unsigned r = idx - b*BSTR;
  unsigned nt = r % CSTR;
  float4 o = *(float4*)(O + idx);
  const float* sp = sden + (size_t)b*CSTR + nt;
  o.x /= sp[0]; o.y /= sp[1]; o.z /= sp[2]; o.w /= sp[3];
  *(float4*)(O + idx) = o;
}

// ---------------------------------------------------------------------------
extern "C" void kernel_launch(void* const* d_in, const int* in_sizes, int n_in,
                              void* d_out, int out_size, void* d_ws, size_t ws_size,
                              hipStream_t stream)
{
  const float* x    = (const float*)d_in[0];
  const float* sup  = (const float*)d_in[1];
  const float* bng  = (const float*)d_in[2];
  const float* bnb  = (const float*)d_in[3];
  const float* rw   = (const float*)d_in[4];
  const float* rb   = (const float*)d_in[5];
  const float* aw   = (const float*)d_in[6];
  const float* ab   = (const float*)d_in[7];
  const float* gw   = (const float*)d_in[8];
  const float* gb   = (const float*)d_in[9];
  const float* gcw  = (const float*)d_in[10];
  const float* gcb  = (const float*)d_in[11];
  const float* w1   = (const float*)d_in[12];
  const float* ab1  = (const float*)d_in[13];
  const float* w2   = (const float*)d_in[14];
  const float* ab2  = (const float*)d_in[15];
  const float* w3   = (const float*)d_in[16];
  const float* ab3  = (const float*)d_in[17];
  float* out = (float*)d_out;

  float* ws   = (float*)d_ws;
  float* bufA = ws;                       // Y0 / layer output h
  float* bufB = ws + TENS;                // Y1
  float* bufC = ws + (size_t)2*TENS;      // Y2
  float* sden = ws + (size_t)3*TENS;      // [B,N,T] softmax denom
  double* st  = (double*)(ws + (size_t)3*TENS + (size_t)B_*N_*T_);
  short* ATh  = (short*)(ws + (size_t)3*TENS + (size_t)B_*N_*T_ + 512);
  short* ATl  = ATh + (size_t)512*1024;
  float* W1T  = (float*)(ATl + (size_t)512*1024);

  zero_kernel<<<1, 256, 0, stream>>>(st);
  aconv_kernel<<<2048, 256, 0, stream>>>(sup, ATh, ATl);
  w1t_kernel<<<8, 256, 0, stream>>>(w1, W1T);
  stats_kernel<<<dim3(C_, B_), 256, 0, stream>>>(x, st);
  // slot 0 of the stack = x
  attn3_kernel<<<B_*125, 256, 0, stream>>>(x, out, sden, W1T, ab1, w2, ab2, w3, ab3, 1);

  const float* hcur = x;
  for (int l = 0; l < L_; l++) {
    fuse3_kernel<<<B_*250, 512, 0, stream>>>(
        hcur, st + l*64, bng + l*C_, bnb + l*C_,
        rw + l*C_*C_, rb + l*C_,
        aw + l*C_*C_*3, ab + l*C_,
        gw + l*C_*C_*3, gb + l*C_,
        gcw + l*C_*96, gcb + l*C_,
        bufA, bufB, bufC);
    diff3_kernel<<<dim3(64, B_), 256, 0, stream>>>(
        bufB, bufC, ATh, ATl, bufA, (l < L_-1) ? (st + (l+1)*64) : nullptr);
    attn3_kernel<<<B_*125, 256, 0, stream>>>(bufA, out, sden, W1T, ab1, w2, ab2, w3, ab3, 0);
    hcur = bufA;
  }
  norm_kernel<<<16000, 256, 0, stream>>>(out, sden);
}